// Round 2
// baseline (73.776 us; speedup 1.0000x reference)
//
#include <hip/hip_runtime.h>

#define HOP      512
#define NHARM    100
#define TFRAMES  400
#define INV_SR   (1.0f / 44100.0f)
#define INV_2PI  0.15915494309189535f

typedef __attribute__((ext_vector_type(2))) float f32x2;

// cos(2*pi*t), t in revolutions (v_fract + v_cos).
__device__ __forceinline__ float cos_rev(float t) {
    return __builtin_amdgcn_cosf(__builtin_amdgcn_fractf(t));
}

__device__ __forceinline__ f32x2 cos_rev2(f32x2 t) {
    f32x2 r;
    r.x = cos_rev(t.x);
    r.y = cos_rev(t.y);
    return r;
}

// Round-2 change: pack the two frame chains (A = frame q, x=r; B = frame
// q+1, x=r-512 folded into phase) into float2 lanes so the Chebyshev
// recurrence + accumulate lower to v_pk_fma_f32 (VOP3P, 2xf32/lane/inst).
// Halves the hot-loop instruction count vs round 1 (12 pk-FMA + 4 pk seed
// ops per harmonic vs ~28 scalar FMA); the 4 fract+cos seeds are
// unchanged (no packed trans pipe).  Structure otherwise as round 1:
// 512-thread block (8 waves) per 512-sample hop chunk, harmonics split
// across waves, 8 samples/lane, __launch_bounds__(512,8) -> 8 waves/SIMD.
__global__ __launch_bounds__(512, 8) void sinstack_kernel(
    const float* __restrict__ ampl,
    const float* __restrict__ phase,
    const float* __restrict__ f0,
    float* __restrict__ out)
{
    const int q    = blockIdx.x;   // 0..399 (hop chunk)
    const int b    = blockIdx.y;   // batch
    const int tid  = threadIdx.x;  // 0..511
    const int wave = tid >> 6;     // 0..7
    const int lane = tid & 63;

    // sP0[n] = {amplA, amplB, frA, frB}   (fr in rev/sample)
    // sP1[n] = {phA, phB, 2cos(2pi frA), 2cos(2pi frB)}  (ph in rev, B shift folded)
    __shared__ float4 sP0[NHARM];
    __shared__ float4 sP1[NHARM];
    // per-wave windowed partials, transposed + padded (65-float rows)
    __shared__ float  sOut[8 * 520];

    if (tid < NHARM) {
        const int n   = tid;
        const int idx = (b * NHARM + n) * TFRAMES + q;
        const bool hasB = (q + 1 < TFRAMES);
        const float aA  = ampl[idx];
        const float aB  = hasB ? ampl[idx + 1] : 0.f;
        const float frA = f0[idx] * INV_SR;
        const float frB = hasB ? f0[idx + 1] * INV_SR : 0.f;
        const float phA = phase[idx] * INV_2PI;
        const float phB = hasB ? (phase[idx + 1] * INV_2PI - 512.0f * frB) : 0.f;
        sP0[n] = make_float4(aA, aB, frA, frB);
        sP1[n] = make_float4(phA, phB, 2.0f * cos_rev(frA), 2.0f * cos_rev(frB));
    }
    __syncthreads();

    const float r0 = (float)(lane * 8);
    const f32x2 r02 = { r0, r0 };
    const int n0 = (wave * NHARM) >> 3;        // 12/13 harmonics per wave
    const int n1 = ((wave + 1) * NHARM) >> 3;

    f32x2 acc[8];
#pragma unroll
    for (int j = 0; j < 8; ++j) acc[j] = (f32x2){ 0.f, 0.f };

    // rotating register prefetch keeps the LDS read off the critical path
    float4 P0 = sP0[n0];
    float4 P1 = sP1[n0];
    for (int n = n0; n < n1; ++n) {
        const int nn = (n + 1 < n1) ? (n + 1) : n0;
        const float4 P0N = sP0[nn];
        const float4 P1N = sP1[nn];

        const f32x2 a2  = { P0.x, P0.y };
        const f32x2 fr2 = { P0.z, P0.w };
        const f32x2 ph2 = { P1.x, P1.y };
        const f32x2 w2  = { P1.z, P1.w };

        const f32x2 t2 = __builtin_elementwise_fma(fr2, r02, ph2);
        f32x2 prev2 = cos_rev2(t2);
        f32x2 cur2  = cos_rev2(t2 + fr2);
        acc[0] = __builtin_elementwise_fma(a2, prev2, acc[0]);
        acc[1] = __builtin_elementwise_fma(a2, cur2,  acc[1]);
#pragma unroll
        for (int j = 2; j < 8; ++j) {
            const f32x2 nxt = __builtin_elementwise_fma(w2, cur2, -prev2);
            acc[j] = __builtin_elementwise_fma(a2, nxt, acc[j]);
            prev2 = cur2; cur2 = nxt;
        }
        P0 = P0N; P1 = P1N;
    }

    // window (linear in partials -> per wave), transposed padded LDS write
    // out = 0.5*((A+B) + c*(A-B)),  c = cos(2*pi*(r0+j)/1024)
    float* myOut = sOut + wave * 520 + lane;
#pragma unroll
    for (int j = 0; j < 8; ++j) {
        const float c = cos_rev((r0 + (float)j) * (1.0f / 1024.0f));
        myOut[j * 65] = 0.5f * ((acc[j].x + acc[j].y) + c * (acc[j].x - acc[j].y));
    }
    __syncthreads();

    // reduce 8 partials; thread t -> sample t, coalesced scalar store
    const int pos = (tid & 7) * 65 + (tid >> 3);   // inverse of transposed layout
    float v = sOut[pos];
#pragma unroll
    for (int w = 1; w < 8; ++w) v += sOut[w * 520 + pos];
    out[(size_t)b * (TFRAMES * HOP) + (size_t)q * HOP + tid] = v;
}

extern "C" void kernel_launch(void* const* d_in, const int* in_sizes, int n_in,
                              void* d_out, int out_size, void* d_ws, size_t ws_size,
                              hipStream_t stream) {
    const float* ampl  = (const float*)d_in[0];
    const float* phase = (const float*)d_in[1];
    const float* f0    = (const float*)d_in[2];
    float* out = (float*)d_out;

    const int B = in_sizes[0] / (NHARM * TFRAMES);  // = 4
    dim3 grid(TFRAMES, B);
    sinstack_kernel<<<grid, 512, 0, stream>>>(ampl, phase, f0, out);
}

// Round 3
// 73.567 us; speedup vs baseline: 1.0028x; 1.0028x over previous
//
#include <hip/hip_runtime.h>

#define HOP      512
#define NHARM    100
#define TFRAMES  400
#define INV_SR   (1.0f / 44100.0f)
#define INV_2PI  0.15915494309189535f

typedef __attribute__((ext_vector_type(2))) float f32x2;

// cos(2*pi*t), t in revolutions (v_fract + v_cos).
__device__ __forceinline__ float cos_rev(float t) {
    return __builtin_amdgcn_cosf(__builtin_amdgcn_fractf(t));
}

__device__ __forceinline__ f32x2 cos_rev2(f32x2 t) {
    f32x2 r;
    r.x = cos_rev(t.x);
    r.y = cos_rev(t.y);
    return r;
}

// Round-3 change (single-variable A/B vs round 2): __launch_bounds__(512,8)
// capped VGPRs at 64 while the hot loop's live set (16 acc + 16 prefetch +
// ~16 temporaries + addressing) needs ~60-70 -> likely scratch spill or
// strangled scheduling, which would explain rounds 1-2's insensitivity to
// both instruction count and occupancy.  Relax to (512,4): VGPR ceiling
// 128, occupancy floor 4 waves/SIMD (round 1 proved 3 vs 8 is irrelevant).
// Everything else identical to round 2.
__global__ __launch_bounds__(512, 4) void sinstack_kernel(
    const float* __restrict__ ampl,
    const float* __restrict__ phase,
    const float* __restrict__ f0,
    float* __restrict__ out)
{
    const int q    = blockIdx.x;   // 0..399 (hop chunk)
    const int b    = blockIdx.y;   // batch
    const int tid  = threadIdx.x;  // 0..511
    const int wave = tid >> 6;     // 0..7
    const int lane = tid & 63;

    // sP0[n] = {amplA, amplB, frA, frB}   (fr in rev/sample)
    // sP1[n] = {phA, phB, 2cos(2pi frA), 2cos(2pi frB)}  (ph in rev, B shift folded)
    __shared__ float4 sP0[NHARM];
    __shared__ float4 sP1[NHARM];
    // per-wave windowed partials, transposed + padded (65-float rows)
    __shared__ float  sOut[8 * 520];

    if (tid < NHARM) {
        const int n   = tid;
        const int idx = (b * NHARM + n) * TFRAMES + q;
        const bool hasB = (q + 1 < TFRAMES);
        const float aA  = ampl[idx];
        const float aB  = hasB ? ampl[idx + 1] : 0.f;
        const float frA = f0[idx] * INV_SR;
        const float frB = hasB ? f0[idx + 1] * INV_SR : 0.f;
        const float phA = phase[idx] * INV_2PI;
        const float phB = hasB ? (phase[idx + 1] * INV_2PI - 512.0f * frB) : 0.f;
        sP0[n] = make_float4(aA, aB, frA, frB);
        sP1[n] = make_float4(phA, phB, 2.0f * cos_rev(frA), 2.0f * cos_rev(frB));
    }
    __syncthreads();

    const float r0 = (float)(lane * 8);
    const f32x2 r02 = { r0, r0 };
    const int n0 = (wave * NHARM) >> 3;        // 12/13 harmonics per wave
    const int n1 = ((wave + 1) * NHARM) >> 3;

    f32x2 acc[8];
#pragma unroll
    for (int j = 0; j < 8; ++j) acc[j] = (f32x2){ 0.f, 0.f };

    // rotating register prefetch keeps the LDS read off the critical path
    float4 P0 = sP0[n0];
    float4 P1 = sP1[n0];
    for (int n = n0; n < n1; ++n) {
        const int nn = (n + 1 < n1) ? (n + 1) : n0;
        const float4 P0N = sP0[nn];
        const float4 P1N = sP1[nn];

        const f32x2 a2  = { P0.x, P0.y };
        const f32x2 fr2 = { P0.z, P0.w };
        const f32x2 ph2 = { P1.x, P1.y };
        const f32x2 w2  = { P1.z, P1.w };

        const f32x2 t2 = __builtin_elementwise_fma(fr2, r02, ph2);
        f32x2 prev2 = cos_rev2(t2);
        f32x2 cur2  = cos_rev2(t2 + fr2);
        acc[0] = __builtin_elementwise_fma(a2, prev2, acc[0]);
        acc[1] = __builtin_elementwise_fma(a2, cur2,  acc[1]);
#pragma unroll
        for (int j = 2; j < 8; ++j) {
            const f32x2 nxt = __builtin_elementwise_fma(w2, cur2, -prev2);
            acc[j] = __builtin_elementwise_fma(a2, nxt, acc[j]);
            prev2 = cur2; cur2 = nxt;
        }
        P0 = P0N; P1 = P1N;
    }

    // window (linear in partials -> per wave), transposed padded LDS write
    // out = 0.5*((A+B) + c*(A-B)),  c = cos(2*pi*(r0+j)/1024)
    float* myOut = sOut + wave * 520 + lane;
#pragma unroll
    for (int j = 0; j < 8; ++j) {
        const float c = cos_rev((r0 + (float)j) * (1.0f / 1024.0f));
        myOut[j * 65] = 0.5f * ((acc[j].x + acc[j].y) + c * (acc[j].x - acc[j].y));
    }
    __syncthreads();

    // reduce 8 partials; thread t -> sample t, coalesced scalar store
    const int pos = (tid & 7) * 65 + (tid >> 3);   // inverse of transposed layout
    float v = sOut[pos];
#pragma unroll
    for (int w = 1; w < 8; ++w) v += sOut[w * 520 + pos];
    out[(size_t)b * (TFRAMES * HOP) + (size_t)q * HOP + tid] = v;
}

extern "C" void kernel_launch(void* const* d_in, const int* in_sizes, int n_in,
                              void* d_out, int out_size, void* d_ws, size_t ws_size,
                              hipStream_t stream) {
    const float* ampl  = (const float*)d_in[0];
    const float* phase = (const float*)d_in[1];
    const float* f0    = (const float*)d_in[2];
    float* out = (float*)d_out;

    const int B = in_sizes[0] / (NHARM * TFRAMES);  // = 4
    dim3 grid(TFRAMES, B);
    sinstack_kernel<<<grid, 512, 0, stream>>>(ampl, phase, f0, out);
}